// Round 5
// baseline (540.514 us; speedup 1.0000x reference)
//
#include <hip/hip_runtime.h>
#include <math.h>

#define IN_DIM 512
#define DD 256
#define NEG_INF -3.402823466e+38f

typedef __attribute__((ext_vector_type(8))) short short8_t;
typedef __attribute__((ext_vector_type(4))) float f32x4_t;

// ---- RNE split: x ~= hi(bf16) + lo(bf16), err ~2^-18 rel ----
__device__ __forceinline__ void split1(float x, ushort& h, ushort& l) {
  unsigned u = __float_as_uint(x);
  unsigned hr = (u + 0x7FFFu + ((u >> 16) & 1u)) >> 16;
  h = (ushort)hr;
  float hf = __uint_as_float(hr << 16);
  float lf = x - hf;
  unsigned ul = __float_as_uint(lf);
  l = (ushort)((ul + 0x7FFFu + ((ul >> 16) & 1u)) >> 16);
}

__device__ __forceinline__ void split8(const float4& a, const float4& b,
                                       short8_t& h, short8_t& l) {
  ushort hh, ll;
  split1(a.x, hh, ll); h[0] = (short)hh; l[0] = (short)ll;
  split1(a.y, hh, ll); h[1] = (short)hh; l[1] = (short)ll;
  split1(a.z, hh, ll); h[2] = (short)hh; l[2] = (short)ll;
  split1(a.w, hh, ll); h[3] = (short)hh; l[3] = (short)ll;
  split1(b.x, hh, ll); h[4] = (short)hh; l[4] = (short)ll;
  split1(b.y, hh, ll); h[5] = (short)hh; l[5] = (short)ll;
  split1(b.z, hh, ll); h[6] = (short)hh; l[6] = (short)ll;
  split1(b.w, hh, ll); h[7] = (short)hh; l[7] = (short)ll;
}

// ---- prep: w2 = W @ a_w[D:2D] ----
__global__ void prep_w2(const float* __restrict__ W, const float* __restrict__ a_w,
                        float* __restrict__ w2) {
  int i = threadIdx.x;  // 0..255
  float s = 0.f;
  for (int j = 0; j < DD; ++j) s = fmaf(W[i * DD + j], a_w[DD + j], s);
  w2[i] = s;
}

// ---- pre-split Wm_o into MFMA-fragment-ordered bf16 hi/lo ----
__global__ void bsplit_kernel(const float* __restrict__ Wm,
                              ushort* __restrict__ Bh, ushort* __restrict__ Bl) {
  int i = blockIdx.x * 256 + threadIdx.x;  // 0..131071
  int k = i >> 8, col = i & 255;
  ushort h, l;
  split1(Wm[i], h, l);
  int kc16 = k >> 5, kr = k & 31;
  int lane = ((kr >> 3) << 4) | (col & 15);
  int nf = col >> 4;
  int off = (((((kc16 << 4) + nf) << 6) + lane) << 3) + (kr & 7);
  Bh[off] = h;
  Bl[off] = l;
}

// ---- MFMA mapping GEMM + fused epilogue: Yn = l2norm(relu(X@Wm+bm));
//      tvals = exp(h.w2), wnorm = tvals * ||h||
// Double-buffered A LDS (one barrier per K-step), 4 blocks/CU. ----
__global__ __launch_bounds__(256, 4) void map_gemm_mfma(
    const float* __restrict__ X, const ushort* __restrict__ Bh,
    const ushort* __restrict__ Bl, const float* __restrict__ bm,
    const float* __restrict__ w2, float* __restrict__ Yn,
    float* __restrict__ tvals, float* __restrict__ wnorm, int M) {
  __shared__ ushort Ah[2][4096];  // 64 rows x 64 k (bf16 hi), XOR-swizzled, dbuf
  __shared__ ushort Al[2][4096];
  const int t = threadIdx.x;
  const int w = t >> 6;
  const int l = t & 63;
  const int c = l & 15;
  const int g = l >> 4;
  const int row0 = blockIdx.x * 64;

  const int sr = t >> 2;
  const int skb = (t & 3) << 4;
  int gr = row0 + sr;
  if (gr >= M) gr = M - 1;
  const float* xrow = X + (size_t)gr * IN_DIM;

  f32x4_t acc[4][4];
#pragma unroll
  for (int m = 0; m < 4; ++m)
#pragma unroll
    for (int n = 0; n < 4; ++n) acc[m][n] = (f32x4_t){0.f, 0.f, 0.f, 0.f};

  const int sw = (sr & 7) << 3;
  const int i0 = ((sr << 6) + skb);
  const short8_t* bhb = reinterpret_cast<const short8_t*>(Bh);
  const short8_t* blb = reinterpret_cast<const short8_t*>(Bl);

  // ---- prologue: stage tile 0 into buf 0 ----
  float4 r0, r1, r2, r3;
  {
    const float4* p = reinterpret_cast<const float4*>(xrow + skb);
    r0 = p[0]; r1 = p[1]; r2 = p[2]; r3 = p[3];
    short8_t h0, h1, l0, l1;
    split8(r0, r1, h0, l0);
    split8(r2, r3, h1, l1);
    *reinterpret_cast<short8_t*>(&Ah[0][i0 ^ sw]) = h0;
    *reinterpret_cast<short8_t*>(&Ah[0][(i0 + 8) ^ sw]) = h1;
    *reinterpret_cast<short8_t*>(&Al[0][i0 ^ sw]) = l0;
    *reinterpret_cast<short8_t*>(&Al[0][(i0 + 8) ^ sw]) = l1;
  }
  __syncthreads();

  for (int ks = 0; ks < 8; ++ks) {
    const int cur = ks & 1;
    // issue next-tile global loads first: latency hides under MFMA phase
    if (ks < 7) {
      const float4* p = reinterpret_cast<const float4*>(xrow + ((ks + 1) << 6) + skb);
      r0 = p[0]; r1 = p[1]; r2 = p[2]; r3 = p[3];
    }

#pragma unroll
    for (int kc = 0; kc < 2; ++kc) {
      const int kc16 = (ks << 1) + kc;
      short8_t ah[4], av[4];
#pragma unroll
      for (int m = 0; m < 4; ++m) {
        int r = (m << 4) + c;
        int idx = ((r << 6) + (kc << 5) + (g << 3)) ^ ((r & 7) << 3);
        ah[m] = *reinterpret_cast<const short8_t*>(&Ah[cur][idx]);
        av[m] = *reinterpret_cast<const short8_t*>(&Al[cur][idx]);
      }
      const int base = (((kc16 << 4) + (w << 2)) << 6) + l;
      short8_t bh = bhb[base], bl = blb[base];
#pragma unroll
      for (int n = 0; n < 4; ++n) {
        short8_t bhn = bh, bln = bl;
        if (n < 3) {  // prefetch next B column fragment
          bhn = bhb[base + ((n + 1) << 6)];
          bln = blb[base + ((n + 1) << 6)];
        }
#pragma unroll
        for (int m = 0; m < 4; ++m) {
          acc[m][n] = __builtin_amdgcn_mfma_f32_16x16x32_bf16(ah[m], bh, acc[m][n], 0, 0, 0);
          acc[m][n] = __builtin_amdgcn_mfma_f32_16x16x32_bf16(ah[m], bl, acc[m][n], 0, 0, 0);
          acc[m][n] = __builtin_amdgcn_mfma_f32_16x16x32_bf16(av[m], bh, acc[m][n], 0, 0, 0);
        }
        bh = bhn; bl = bln;
      }
    }

    // split + write next tile into the other buffer (prev reads of that
    // buffer completed before last iteration's barrier)
    if (ks < 7) {
      short8_t h0, h1, l0, l1;
      split8(r0, r1, h0, l0);
      split8(r2, r3, h1, l1);
      const int nxt = cur ^ 1;
      *reinterpret_cast<short8_t*>(&Ah[nxt][i0 ^ sw]) = h0;
      *reinterpret_cast<short8_t*>(&Ah[nxt][(i0 + 8) ^ sw]) = h1;
      *reinterpret_cast<short8_t*>(&Al[nxt][i0 ^ sw]) = l0;
      *reinterpret_cast<short8_t*>(&Al[nxt][(i0 + 8) ^ sw]) = l1;
    }
    __syncthreads();
  }

  // ---- epilogue: bias+relu, fused row-dot + row-norm, exp, normalized store ----
  float bv[4], wv[4];
#pragma unroll
  for (int n = 0; n < 4; ++n) {
    bv[n] = bm[(w << 6) + (n << 4) + c];
    wv[n] = w2[(w << 6) + (n << 4) + c];
  }
#pragma unroll
  for (int m = 0; m < 4; ++m)
#pragma unroll
    for (int n = 0; n < 4; ++n)
#pragma unroll
      for (int q = 0; q < 4; ++q) {
        float v = acc[m][n][q] + bv[n];
        acc[m][n][q] = v > 0.f ? v : 0.f;
      }

  float* red = reinterpret_cast<float*>(&Ah[0][0]);
  float pss[4][4], pdt[4][4];
#pragma unroll
  for (int m = 0; m < 4; ++m)
#pragma unroll
    for (int q = 0; q < 4; ++q) {
      float ss = 0.f, dt = 0.f;
#pragma unroll
      for (int n = 0; n < 4; ++n) {
        float a = acc[m][n][q];
        ss = fmaf(a, a, ss);
        dt = fmaf(a, wv[n], dt);
      }
      for (int d = 8; d; d >>= 1) {
        ss += __shfl_down(ss, d, 16);
        dt += __shfl_down(dt, d, 16);
      }
      pss[m][q] = ss;
      pdt[m][q] = dt;
    }
  __syncthreads();
#pragma unroll
  for (int m = 0; m < 4; ++m)
#pragma unroll
    for (int q = 0; q < 4; ++q)
      if (c == 0) {
        int rr = (m << 4) + (g << 2) + q;
        red[(w << 6) + rr] = pss[m][q];
        red[256 + (w << 6) + rr] = pdt[m][q];
      }
  __syncthreads();
  if (t < 64) {
    float ss = red[t] + red[64 + t] + red[128 + t] + red[192 + t];
    float dt = red[256 + t] + red[320 + t] + red[384 + t] + red[448 + t];
    float nr = sqrtf(ss);
    red[512 + t] = 1.f / fmaxf(nr, 1e-12f);
    int r = row0 + t;
    if (r < M) {
      float tv = expf(dt);
      tvals[r] = tv;
      wnorm[r] = tv * nr;
    }
  }
  __syncthreads();
#pragma unroll
  for (int m = 0; m < 4; ++m)
#pragma unroll
    for (int q = 0; q < 4; ++q) {
      int rr = (m << 4) + (g << 2) + q;
      float sc = red[512 + rr];
      int r = row0 + rr;
      if (r < M) {
#pragma unroll
        for (int n = 0; n < 4; ++n)
          Yn[(size_t)r * DD + (w << 6) + (n << 4) + c] = acc[m][n][q] * sc;
      }
    }
}

// ---- CSR build ----
__global__ void hist_kernel(const int* __restrict__ src, int* __restrict__ deg, int E) {
  int i = blockIdx.x * blockDim.x + threadIdx.x;
  if (i < E) atomicAdd(&deg[src[i]], 1);
}

// hierarchical exclusive scan: 256 blocks x 256 thr x 2 items
__global__ __launch_bounds__(256) void scan_part(const int* __restrict__ deg,
                                                 int* __restrict__ bsum, int NP) {
  __shared__ int s[256];
  int t = threadIdx.x, b = blockIdx.x;
  int i0 = (b * 256 + t) * 2;
  int v0 = (i0 < NP) ? deg[i0] : 0;
  int v1 = (i0 + 1 < NP) ? deg[i0 + 1] : 0;
  s[t] = v0 + v1;
  __syncthreads();
  for (int off = 128; off; off >>= 1) {
    if (t < off) s[t] += s[t + off];
    __syncthreads();
  }
  if (t == 0) bsum[b] = s[0];
}

__global__ __launch_bounds__(256) void scan_top(int* __restrict__ bsum,
                                                int* __restrict__ rowptr_last) {
  __shared__ int s[256];
  int t = threadIdx.x;
  int v = bsum[t];
  s[t] = v;
  __syncthreads();
  for (int off = 1; off < 256; off <<= 1) {
    int u = (t >= off) ? s[t - off] : 0;
    __syncthreads();
    s[t] += u;
    __syncthreads();
  }
  bsum[t] = s[t] - v;  // exclusive
  if (t == 255) *rowptr_last = s[255];
}

__global__ __launch_bounds__(256) void scan_fin(const int* __restrict__ deg,
                                                const int* __restrict__ bsum,
                                                int* __restrict__ rowptr,
                                                int* __restrict__ cursor, int NP) {
  __shared__ int s[256];
  int t = threadIdx.x, b = blockIdx.x;
  int i0 = (b * 256 + t) * 2;
  int v0 = (i0 < NP) ? deg[i0] : 0;
  int v1 = (i0 + 1 < NP) ? deg[i0 + 1] : 0;
  int local = v0 + v1;
  s[t] = local;
  __syncthreads();
  for (int off = 1; off < 256; off <<= 1) {
    int u = (t >= off) ? s[t - off] : 0;
    __syncthreads();
    s[t] += u;
    __syncthreads();
  }
  int base = bsum[b] + s[t] - local;
  if (i0 < NP) { rowptr[i0] = base; cursor[i0] = base; }
  if (i0 + 1 < NP) { rowptr[i0 + 1] = base + v0; cursor[i0 + 1] = base + v0; }
}

__global__ void fill_kernel(const int* __restrict__ src, const int* __restrict__ dst,
                            int* __restrict__ cursor, int* __restrict__ ebuf, int E) {
  int i = blockIdx.x * blockDim.x + threadIdx.x;
  if (i < E) {
    int pos = atomicAdd(&cursor[src[i]], 1);
    ebuf[pos] = dst[i];
  }
}

// ---- per-segment: denom = sum t[dst]; agg = sum (wn[dst]/denom) * hon[dst]; l2norm ----
__global__ void agg_kernel(const int* __restrict__ rowptr, const int* __restrict__ ebuf,
                           const float* __restrict__ tvals, const float* __restrict__ wnorm,
                           const float* __restrict__ hon, float* __restrict__ agg, int NP) {
  int p = (int)(((long)blockIdx.x * blockDim.x + threadIdx.x) >> 6);
  int lane = threadIdx.x & 63;
  if (p >= NP) return;
  int beg = rowptr[p], end = rowptr[p + 1];
  float4 acc = {0.f, 0.f, 0.f, 0.f};
  if (beg < end) {
    // lane-parallel denom (no max shift: scores are O(0.1))
    float den = 0.f;
    for (int j = beg + lane; j < end; j += 64) den += tvals[ebuf[j]];
#pragma unroll
    for (int d = 32; d > 0; d >>= 1) den += __shfl_xor(den, d, 64);
    float inv = 1.f / den;
    // 1-deep pipelined weighted row gather
    int d0 = ebuf[beg];
    float wcur = wnorm[d0];
    float4 v = *reinterpret_cast<const float4*>(&hon[(size_t)d0 * DD + lane * 4]);
    for (int j = beg + 1; j <= end; ++j) {
      float4 vn = {0.f, 0.f, 0.f, 0.f};
      float wnext = 0.f;
      if (j < end) {
        int dn = ebuf[j];
        wnext = wnorm[dn];
        vn = *reinterpret_cast<const float4*>(&hon[(size_t)dn * DD + lane * 4]);
      }
      float wa = wcur * inv;
      acc.x = fmaf(wa, v.x, acc.x);
      acc.y = fmaf(wa, v.y, acc.y);
      acc.z = fmaf(wa, v.z, acc.z);
      acc.w = fmaf(wa, v.w, acc.w);
      v = vn; wcur = wnext;
    }
  }
  float ss = acc.x * acc.x + acc.y * acc.y + acc.z * acc.z + acc.w * acc.w;
#pragma unroll
  for (int d = 32; d > 0; d >>= 1) ss += __shfl_xor(ss, d, 64);
  float inv = 1.0f / fmaxf(sqrtf(ss), 1e-12f);
  float4 o = {acc.x * inv, acc.y * inv, acc.z * inv, acc.w * inv};
  *reinterpret_cast<float4*>(&agg[(size_t)p * DD + lane * 4]) = o;
}

extern "C" void kernel_launch(void* const* d_in, const int* in_sizes, int n_in,
                              void* d_out, int out_size, void* d_ws, size_t ws_size,
                              hipStream_t stream) {
  const float* feat_other = (const float*)d_in[1];
  const int* src = (const int*)d_in[2];
  const int* dst = (const int*)d_in[3];
  const float* Wm_o = (const float*)d_in[6];
  const float* bm_o = (const float*)d_in[7];
  const float* W = (const float*)d_in[8];
  const float* a_w = (const float*)d_in[10];

  const int NP = in_sizes[0] / IN_DIM;
  const int NO = in_sizes[1] / IN_DIM;
  const int E = in_sizes[2];

  float* out = (float*)d_out;
  float* agg_out = out;                      // [NP, DD] (normalized agg)
  float* ho_out = out + (size_t)NP * DD;     // [NO, DD] (normalized ho)

  // workspace layout (floats)
  float* ws = (float*)d_ws;
  float* tvals = ws;                          // NO
  float* wnorm = tvals + NO;                  // NO
  float* w2 = wnorm + NO;                     // 256
  int* deg = (int*)(w2 + 256);                // NP (memset 0)
  int* rowptr = deg + NP;                     // NP+1
  int* cursor = rowptr + NP + 1;              // NP
  int* bsum = cursor + NP;                    // 256
  int* ebuf = bsum + 256;                     // E
  size_t foff = (size_t)(2 * NO) + 256 + NP + (NP + 1) + NP + 256 + E;
  foff = (foff + 3) & ~(size_t)3;             // 16B align
  ushort* Bh = (ushort*)(ws + foff);          // 131072 ushorts
  ushort* Bl = Bh + (size_t)IN_DIM * DD;      // 131072 ushorts

  hipMemsetAsync(deg, 0, (size_t)NP * sizeof(int), stream);

  prep_w2<<<1, 256, 0, stream>>>(W, a_w, w2);
  bsplit_kernel<<<(IN_DIM * DD) / 256, 256, 0, stream>>>(Wm_o, Bh, Bl);

  map_gemm_mfma<<<(NO + 63) / 64, 256, 0, stream>>>(
      feat_other, Bh, Bl, bm_o, w2, ho_out, tvals, wnorm, NO);

  hist_kernel<<<(E + 255) / 256, 256, 0, stream>>>(src, deg, E);
  scan_part<<<256, 256, 0, stream>>>(deg, bsum, NP);
  scan_top<<<1, 256, 0, stream>>>(bsum, rowptr + NP);
  scan_fin<<<256, 256, 0, stream>>>(deg, bsum, rowptr, cursor, NP);
  fill_kernel<<<(E + 255) / 256, 256, 0, stream>>>(src, dst, cursor, ebuf, E);

  agg_kernel<<<(NP * 64 + 255) / 256, 256, 0, stream>>>(
      rowptr, ebuf, tvals, wnorm, ho_out, agg_out, NP);
}

// Round 6
// 401.684 us; speedup vs baseline: 1.3456x; 1.3456x over previous
//
#include <hip/hip_runtime.h>
#include <math.h>

#define IN_DIM 512
#define DD 256
#define NEG_INF -3.402823466e+38f

typedef __attribute__((ext_vector_type(8))) short short8_t;
typedef __attribute__((ext_vector_type(4))) float f32x4_t;

// ---- RNE split: x ~= hi(bf16) + lo(bf16), err ~2^-18 rel ----
__device__ __forceinline__ void split1(float x, ushort& h, ushort& l) {
  unsigned u = __float_as_uint(x);
  unsigned hr = (u + 0x7FFFu + ((u >> 16) & 1u)) >> 16;
  h = (ushort)hr;
  float hf = __uint_as_float(hr << 16);
  float lf = x - hf;
  l = (ushort)(__float_as_uint(lf) >> 16);  // truncate lo: err 2^-16 overall
}

__device__ __forceinline__ void split8(const float4& a, const float4& b,
                                       short8_t& h, short8_t& l) {
  ushort hh, ll;
  split1(a.x, hh, ll); h[0] = (short)hh; l[0] = (short)ll;
  split1(a.y, hh, ll); h[1] = (short)hh; l[1] = (short)ll;
  split1(a.z, hh, ll); h[2] = (short)hh; l[2] = (short)ll;
  split1(a.w, hh, ll); h[3] = (short)hh; l[3] = (short)ll;
  split1(b.x, hh, ll); h[4] = (short)hh; l[4] = (short)ll;
  split1(b.y, hh, ll); h[5] = (short)hh; l[5] = (short)ll;
  split1(b.z, hh, ll); h[6] = (short)hh; l[6] = (short)ll;
  split1(b.w, hh, ll); h[7] = (short)hh; l[7] = (short)ll;
}

// ---- prep: w2 = W @ a_w[D:2D] ----
__global__ void prep_w2(const float* __restrict__ W, const float* __restrict__ a_w,
                        float* __restrict__ w2) {
  int i = threadIdx.x;  // 0..255
  float s = 0.f;
  for (int j = 0; j < DD; ++j) s = fmaf(W[i * DD + j], a_w[DD + j], s);
  w2[i] = s;
}

// ---- pre-split Wm_o into MFMA-fragment-ordered bf16 hi/lo (RNE both) ----
__global__ void bsplit_kernel(const float* __restrict__ Wm,
                              ushort* __restrict__ Bh, ushort* __restrict__ Bl) {
  int i = blockIdx.x * 256 + threadIdx.x;  // 0..131071
  int k = i >> 8, col = i & 255;
  float x = Wm[i];
  unsigned u = __float_as_uint(x);
  unsigned hr = (u + 0x7FFFu + ((u >> 16) & 1u)) >> 16;
  float hf = __uint_as_float(hr << 16);
  float lf = x - hf;
  unsigned ul = __float_as_uint(lf);
  ushort l = (ushort)((ul + 0x7FFFu + ((ul >> 16) & 1u)) >> 16);
  int kc16 = k >> 5, kr = k & 31;
  int lane = ((kr >> 3) << 4) | (col & 15);
  int nf = col >> 4;
  int off = (((((kc16 << 4) + nf) << 6) + lane) << 3) + (kr & 7);
  Bh[off] = (ushort)hr;
  Bl[off] = l;
}

// ---- MFMA mapping GEMM + fused epilogue: Yn = l2norm(relu(X@Wm+bm));
//      tvals = exp(h.w2), wnorm = tvals * ||h||
// Double-buffered A LDS, one barrier per K-step, regs unconstrained. ----
__global__ __launch_bounds__(256, 2) void map_gemm_mfma(
    const float* __restrict__ X, const ushort* __restrict__ Bh,
    const ushort* __restrict__ Bl, const float* __restrict__ bm,
    const float* __restrict__ w2, float* __restrict__ Yn,
    float* __restrict__ tvals, float* __restrict__ wnorm, int M) {
  __shared__ ushort Ah[2][4096];  // 64 rows x 64 k (bf16 hi), XOR-swizzled, dbuf
  __shared__ ushort Al[2][4096];
  const int t = threadIdx.x;
  const int w = t >> 6;
  const int l = t & 63;
  const int c = l & 15;
  const int g = l >> 4;
  const int row0 = blockIdx.x * 64;

  const int sr = t >> 2;
  const int skb = (t & 3) << 4;
  int gr = row0 + sr;
  if (gr >= M) gr = M - 1;
  const float* xrow = X + (size_t)gr * IN_DIM;

  f32x4_t acc[4][4];
#pragma unroll
  for (int m = 0; m < 4; ++m)
#pragma unroll
    for (int n = 0; n < 4; ++n) acc[m][n] = (f32x4_t){0.f, 0.f, 0.f, 0.f};

  const int sw = (sr & 7) << 3;
  const int i0 = ((sr << 6) + skb);
  const short8_t* bhb = reinterpret_cast<const short8_t*>(Bh);
  const short8_t* blb = reinterpret_cast<const short8_t*>(Bl);

  // ---- prologue: stage tile 0 into buf 0 ----
  float4 r0, r1, r2, r3;
  {
    const float4* p = reinterpret_cast<const float4*>(xrow + skb);
    r0 = p[0]; r1 = p[1]; r2 = p[2]; r3 = p[3];
    short8_t h0, h1, l0, l1;
    split8(r0, r1, h0, l0);
    split8(r2, r3, h1, l1);
    *reinterpret_cast<short8_t*>(&Ah[0][i0 ^ sw]) = h0;
    *reinterpret_cast<short8_t*>(&Ah[0][(i0 + 8) ^ sw]) = h1;
    *reinterpret_cast<short8_t*>(&Al[0][i0 ^ sw]) = l0;
    *reinterpret_cast<short8_t*>(&Al[0][(i0 + 8) ^ sw]) = l1;
  }
  __syncthreads();

  for (int ks = 0; ks < 8; ++ks) {
    const int cur = ks & 1;
    // issue next-tile global loads first: latency hides under MFMA phase
    if (ks < 7) {
      const float4* p = reinterpret_cast<const float4*>(xrow + ((ks + 1) << 6) + skb);
      r0 = p[0]; r1 = p[1]; r2 = p[2]; r3 = p[3];
    }

#pragma unroll
    for (int kc = 0; kc < 2; ++kc) {
      const int kc16 = (ks << 1) + kc;
      short8_t ah[4], av[4];
#pragma unroll
      for (int m = 0; m < 4; ++m) {
        int r = (m << 4) + c;
        int idx = ((r << 6) + (kc << 5) + (g << 3)) ^ ((r & 7) << 3);
        ah[m] = *reinterpret_cast<const short8_t*>(&Ah[cur][idx]);
        av[m] = *reinterpret_cast<const short8_t*>(&Al[cur][idx]);
      }
      short8_t bh[4], bl[4];
#pragma unroll
      for (int n = 0; n < 4; ++n) {
        const int boff = (((kc16 << 4) + (w << 2) + n) << 6) + l;
        bh[n] = bhb[boff];
        bl[n] = blb[boff];
      }
#pragma unroll
      for (int n = 0; n < 4; ++n)
#pragma unroll
        for (int m = 0; m < 4; ++m) {
          acc[m][n] = __builtin_amdgcn_mfma_f32_16x16x32_bf16(ah[m], bh[n], acc[m][n], 0, 0, 0);
          acc[m][n] = __builtin_amdgcn_mfma_f32_16x16x32_bf16(ah[m], bl[n], acc[m][n], 0, 0, 0);
          acc[m][n] = __builtin_amdgcn_mfma_f32_16x16x32_bf16(av[m], bh[n], acc[m][n], 0, 0, 0);
        }
    }

    // split + write next tile into the other buffer
    if (ks < 7) {
      short8_t h0, h1, l0, l1;
      split8(r0, r1, h0, l0);
      split8(r2, r3, h1, l1);
      const int nxt = cur ^ 1;
      *reinterpret_cast<short8_t*>(&Ah[nxt][i0 ^ sw]) = h0;
      *reinterpret_cast<short8_t*>(&Ah[nxt][(i0 + 8) ^ sw]) = h1;
      *reinterpret_cast<short8_t*>(&Al[nxt][i0 ^ sw]) = l0;
      *reinterpret_cast<short8_t*>(&Al[nxt][(i0 + 8) ^ sw]) = l1;
    }
    __syncthreads();
  }

  // ---- epilogue: bias+relu, fused row-dot + row-norm, exp, normalized store ----
  float bv[4], wv[4];
#pragma unroll
  for (int n = 0; n < 4; ++n) {
    bv[n] = bm[(w << 6) + (n << 4) + c];
    wv[n] = w2[(w << 6) + (n << 4) + c];
  }
#pragma unroll
  for (int m = 0; m < 4; ++m)
#pragma unroll
    for (int n = 0; n < 4; ++n)
#pragma unroll
      for (int q = 0; q < 4; ++q) {
        float v = acc[m][n][q] + bv[n];
        acc[m][n][q] = v > 0.f ? v : 0.f;
      }

  float* red = reinterpret_cast<float*>(&Ah[0][0]);
  float pss[4][4], pdt[4][4];
#pragma unroll
  for (int m = 0; m < 4; ++m)
#pragma unroll
    for (int q = 0; q < 4; ++q) {
      float ss = 0.f, dt = 0.f;
#pragma unroll
      for (int n = 0; n < 4; ++n) {
        float a = acc[m][n][q];
        ss = fmaf(a, a, ss);
        dt = fmaf(a, wv[n], dt);
      }
      for (int d = 8; d; d >>= 1) {
        ss += __shfl_down(ss, d, 16);
        dt += __shfl_down(dt, d, 16);
      }
      pss[m][q] = ss;
      pdt[m][q] = dt;
    }
  __syncthreads();
#pragma unroll
  for (int m = 0; m < 4; ++m)
#pragma unroll
    for (int q = 0; q < 4; ++q)
      if (c == 0) {
        int rr = (m << 4) + (g << 2) + q;
        red[(w << 6) + rr] = pss[m][q];
        red[256 + (w << 6) + rr] = pdt[m][q];
      }
  __syncthreads();
  if (t < 64) {
    float ss = red[t] + red[64 + t] + red[128 + t] + red[192 + t];
    float dt = red[256 + t] + red[320 + t] + red[384 + t] + red[448 + t];
    float nr = sqrtf(ss);
    red[512 + t] = 1.f / fmaxf(nr, 1e-12f);
    int r = row0 + t;
    if (r < M) {
      float tv = expf(dt);
      tvals[r] = tv;
      wnorm[r] = tv * nr;
    }
  }
  __syncthreads();
#pragma unroll
  for (int m = 0; m < 4; ++m)
#pragma unroll
    for (int q = 0; q < 4; ++q) {
      int rr = (m << 4) + (g << 2) + q;
      float sc = red[512 + rr];
      int r = row0 + rr;
      if (r < M) {
#pragma unroll
        for (int n = 0; n < 4; ++n)
          Yn[(size_t)r * DD + (w << 6) + (n << 4) + c] = acc[m][n][q] * sc;
      }
    }
}

// ---- CSR build ----
__global__ void hist_kernel(const int* __restrict__ src, int* __restrict__ deg, int E) {
  int i = blockIdx.x * blockDim.x + threadIdx.x;
  if (i < E) atomicAdd(&deg[src[i]], 1);
}

// hierarchical exclusive scan: 256 blocks x 256 thr x 2 items
__global__ __launch_bounds__(256) void scan_part(const int* __restrict__ deg,
                                                 int* __restrict__ bsum, int NP) {
  __shared__ int s[256];
  int t = threadIdx.x, b = blockIdx.x;
  int i0 = (b * 256 + t) * 2;
  int v0 = (i0 < NP) ? deg[i0] : 0;
  int v1 = (i0 + 1 < NP) ? deg[i0 + 1] : 0;
  s[t] = v0 + v1;
  __syncthreads();
  for (int off = 128; off; off >>= 1) {
    if (t < off) s[t] += s[t + off];
    __syncthreads();
  }
  if (t == 0) bsum[b] = s[0];
}

__global__ __launch_bounds__(256) void scan_top(int* __restrict__ bsum,
                                                int* __restrict__ rowptr_last) {
  __shared__ int s[256];
  int t = threadIdx.x;
  int v = bsum[t];
  s[t] = v;
  __syncthreads();
  for (int off = 1; off < 256; off <<= 1) {
    int u = (t >= off) ? s[t - off] : 0;
    __syncthreads();
    s[t] += u;
    __syncthreads();
  }
  bsum[t] = s[t] - v;  // exclusive
  if (t == 255) *rowptr_last = s[255];
}

__global__ __launch_bounds__(256) void scan_fin(const int* __restrict__ deg,
                                                const int* __restrict__ bsum,
                                                int* __restrict__ rowptr,
                                                int* __restrict__ cursor, int NP) {
  __shared__ int s[256];
  int t = threadIdx.x, b = blockIdx.x;
  int i0 = (b * 256 + t) * 2;
  int v0 = (i0 < NP) ? deg[i0] : 0;
  int v1 = (i0 + 1 < NP) ? deg[i0 + 1] : 0;
  int local = v0 + v1;
  s[t] = local;
  __syncthreads();
  for (int off = 1; off < 256; off <<= 1) {
    int u = (t >= off) ? s[t - off] : 0;
    __syncthreads();
    s[t] += u;
    __syncthreads();
  }
  int base = bsum[b] + s[t] - local;
  if (i0 < NP) { rowptr[i0] = base; cursor[i0] = base; }
  if (i0 + 1 < NP) { rowptr[i0 + 1] = base + v0; cursor[i0 + 1] = base + v0; }
}

__global__ void fill_kernel(const int* __restrict__ src, const int* __restrict__ dst,
                            int* __restrict__ cursor, int* __restrict__ ebuf, int E) {
  int i = blockIdx.x * blockDim.x + threadIdx.x;
  if (i < E) {
    int pos = atomicAdd(&cursor[src[i]], 1);
    ebuf[pos] = dst[i];
  }
}

// ---- per-segment: denom = sum t[dst]; agg = sum (wn[dst]/denom) * hon[dst]; l2norm ----
__global__ void agg_kernel(const int* __restrict__ rowptr, const int* __restrict__ ebuf,
                           const float* __restrict__ tvals, const float* __restrict__ wnorm,
                           const float* __restrict__ hon, float* __restrict__ agg, int NP) {
  int p = (int)(((long)blockIdx.x * blockDim.x + threadIdx.x) >> 6);
  int lane = threadIdx.x & 63;
  if (p >= NP) return;
  int beg = rowptr[p], end = rowptr[p + 1];
  float4 acc = {0.f, 0.f, 0.f, 0.f};
  if (beg < end) {
    // lane-parallel denom (no max shift: scores are O(0.1))
    float den = 0.f;
    for (int j = beg + lane; j < end; j += 64) den += tvals[ebuf[j]];
#pragma unroll
    for (int d = 32; d > 0; d >>= 1) den += __shfl_xor(den, d, 64);
    float inv = 1.f / den;
    // 1-deep pipelined weighted row gather
    int d0 = ebuf[beg];
    float wcur = wnorm[d0];
    float4 v = *reinterpret_cast<const float4*>(&hon[(size_t)d0 * DD + lane * 4]);
    for (int j = beg + 1; j <= end; ++j) {
      float4 vn = {0.f, 0.f, 0.f, 0.f};
      float wnext = 0.f;
      if (j < end) {
        int dn = ebuf[j];
        wnext = wnorm[dn];
        vn = *reinterpret_cast<const float4*>(&hon[(size_t)dn * DD + lane * 4]);
      }
      float wa = wcur * inv;
      acc.x = fmaf(wa, v.x, acc.x);
      acc.y = fmaf(wa, v.y, acc.y);
      acc.z = fmaf(wa, v.z, acc.z);
      acc.w = fmaf(wa, v.w, acc.w);
      v = vn; wcur = wnext;
    }
  }
  float ss = acc.x * acc.x + acc.y * acc.y + acc.z * acc.z + acc.w * acc.w;
#pragma unroll
  for (int d = 32; d > 0; d >>= 1) ss += __shfl_xor(ss, d, 64);
  float inv = 1.0f / fmaxf(sqrtf(ss), 1e-12f);
  float4 o = {acc.x * inv, acc.y * inv, acc.z * inv, acc.w * inv};
  *reinterpret_cast<float4*>(&agg[(size_t)p * DD + lane * 4]) = o;
}

extern "C" void kernel_launch(void* const* d_in, const int* in_sizes, int n_in,
                              void* d_out, int out_size, void* d_ws, size_t ws_size,
                              hipStream_t stream) {
  const float* feat_other = (const float*)d_in[1];
  const int* src = (const int*)d_in[2];
  const int* dst = (const int*)d_in[3];
  const float* Wm_o = (const float*)d_in[6];
  const float* bm_o = (const float*)d_in[7];
  const float* W = (const float*)d_in[8];
  const float* a_w = (const float*)d_in[10];

  const int NP = in_sizes[0] / IN_DIM;
  const int NO = in_sizes[1] / IN_DIM;
  const int E = in_sizes[2];

  float* out = (float*)d_out;
  float* agg_out = out;                      // [NP, DD] (normalized agg)
  float* ho_out = out + (size_t)NP * DD;     // [NO, DD] (normalized ho)

  // workspace layout (floats)
  float* ws = (float*)d_ws;
  float* tvals = ws;                          // NO
  float* wnorm = tvals + NO;                  // NO
  float* w2 = wnorm + NO;                     // 256
  int* deg = (int*)(w2 + 256);                // NP (memset 0)
  int* rowptr = deg + NP;                     // NP+1
  int* cursor = rowptr + NP + 1;              // NP
  int* bsum = cursor + NP;                    // 256
  int* ebuf = bsum + 256;                     // E
  size_t foff = (size_t)(2 * NO) + 256 + NP + (NP + 1) + NP + 256 + E;
  foff = (foff + 3) & ~(size_t)3;             // 16B align
  ushort* Bh = (ushort*)(ws + foff);          // 131072 ushorts
  ushort* Bl = Bh + (size_t)IN_DIM * DD;      // 131072 ushorts

  hipMemsetAsync(deg, 0, (size_t)NP * sizeof(int), stream);

  prep_w2<<<1, 256, 0, stream>>>(W, a_w, w2);
  bsplit_kernel<<<(IN_DIM * DD) / 256, 256, 0, stream>>>(Wm_o, Bh, Bl);

  map_gemm_mfma<<<(NO + 63) / 64, 256, 0, stream>>>(
      feat_other, Bh, Bl, bm_o, w2, ho_out, tvals, wnorm, NO);

  hist_kernel<<<(E + 255) / 256, 256, 0, stream>>>(src, deg, E);
  scan_part<<<256, 256, 0, stream>>>(deg, bsum, NP);
  scan_top<<<1, 256, 0, stream>>>(bsum, rowptr + NP);
  scan_fin<<<256, 256, 0, stream>>>(deg, bsum, rowptr, cursor, NP);
  fill_kernel<<<(E + 255) / 256, 256, 0, stream>>>(src, dst, cursor, ebuf, E);

  agg_kernel<<<(NP * 64 + 255) / 256, 256, 0, stream>>>(
      rowptr, ebuf, tvals, wnorm, ho_out, agg_out, NP);
}

// Round 7
// 385.876 us; speedup vs baseline: 1.4007x; 1.0410x over previous
//
#include <hip/hip_runtime.h>
#include <math.h>

#define IN_DIM 512
#define DD 256

typedef _Float16 half8_t __attribute__((ext_vector_type(8)));
typedef __attribute__((ext_vector_type(4))) float f32x4_t;

// ---- prep: w2 = W @ a_w[D:2D] ----
__global__ void prep_w2(const float* __restrict__ W, const float* __restrict__ a_w,
                        float* __restrict__ w2) {
  int i = threadIdx.x;  // 0..255
  float s = 0.f;
  for (int j = 0; j < DD; ++j) s = fmaf(W[i * DD + j], a_w[DD + j], s);
  w2[i] = s;
}

// ---- convert Wm_o to MFMA-fragment-ordered fp16 ----
// frag element: b[j] = B[k][col], k = kc16*32 + (lane>>4)*8 + j, col = nf*16 + (lane&15)
__global__ void bconv_kernel(const float* __restrict__ Wm, _Float16* __restrict__ Bh) {
  int i = blockIdx.x * 256 + threadIdx.x;  // 0..131071
  int k = i >> 8, col = i & 255;
  int kc16 = k >> 5, kr = k & 31;
  int lane = ((kr >> 3) << 4) | (col & 15);
  int nf = col >> 4;
  int off = (((((kc16 << 4) + nf) << 6) + lane) << 3) + (kr & 7);
  Bh[off] = (_Float16)Wm[i];
}

__device__ __forceinline__ half8_t cvt8(const float4& a, const float4& b) {
  half8_t h;
  h[0] = (_Float16)a.x; h[1] = (_Float16)a.y; h[2] = (_Float16)a.z; h[3] = (_Float16)a.w;
  h[4] = (_Float16)b.x; h[5] = (_Float16)b.y; h[6] = (_Float16)b.z; h[7] = (_Float16)b.w;
  return h;
}

// ---- fp16 single-pass MFMA GEMM + fused epilogue:
//      Yn = l2norm(relu(X@Wm+bm)); wnorm = exp(h.w2) * ||h||
// 64 rows x 256 cols per block, BK=128, double-buffered A LDS. ----
__global__ __launch_bounds__(256, 2) void map_gemm_mfma(
    const float* __restrict__ X, const _Float16* __restrict__ Bh,
    const float* __restrict__ bm, const float* __restrict__ w2,
    float* __restrict__ Yn, float* __restrict__ wnorm, int M) {
  __shared__ ushort Ah[2][8192];  // 64 rows x 128 k fp16, XOR-swizzled, dbuf
  const int t = threadIdx.x;
  const int w = t >> 6;
  const int l = t & 63;
  const int c = l & 15;
  const int g = l >> 4;
  const int row0 = blockIdx.x * 64;

  // A staging: thread -> row t>>2, 32 consecutive k at (t&3)*32
  const int sr = t >> 2;
  const int skb = (t & 3) << 5;
  int gr = row0 + sr;
  if (gr >= M) gr = M - 1;
  const float* xrow = X + (size_t)gr * IN_DIM;

  f32x4_t acc[4][4];
#pragma unroll
  for (int m = 0; m < 4; ++m)
#pragma unroll
    for (int n = 0; n < 4; ++n) acc[m][n] = (f32x4_t){0.f, 0.f, 0.f, 0.f};

  const int sw = (sr & 15) << 3;       // ushort-index XOR (16B granules)
  const int i0 = (sr << 7) + skb;
  const half8_t* bhb = reinterpret_cast<const half8_t*>(Bh);

  // ---- prologue: stage K-tile 0 into buf 0 ----
  float4 r0, r1, r2, r3, r4, r5, r6, r7;
  {
    const float4* p = reinterpret_cast<const float4*>(xrow + skb);
    r0 = p[0]; r1 = p[1]; r2 = p[2]; r3 = p[3];
    r4 = p[4]; r5 = p[5]; r6 = p[6]; r7 = p[7];
    *reinterpret_cast<half8_t*>(&Ah[0][(i0 + 0) ^ sw]) = cvt8(r0, r1);
    *reinterpret_cast<half8_t*>(&Ah[0][(i0 + 8) ^ sw]) = cvt8(r2, r3);
    *reinterpret_cast<half8_t*>(&Ah[0][(i0 + 16) ^ sw]) = cvt8(r4, r5);
    *reinterpret_cast<half8_t*>(&Ah[0][(i0 + 24) ^ sw]) = cvt8(r6, r7);
  }
  __syncthreads();

  for (int ks = 0; ks < 4; ++ks) {
    const int cur = ks & 1;
    // issue next-tile global loads first: latency hides under MFMA phase
    if (ks < 3) {
      const float4* p = reinterpret_cast<const float4*>(xrow + ((ks + 1) << 7) + skb);
      r0 = p[0]; r1 = p[1]; r2 = p[2]; r3 = p[3];
      r4 = p[4]; r5 = p[5]; r6 = p[6]; r7 = p[7];
    }

#pragma unroll
    for (int kc = 0; kc < 4; ++kc) {
      const int kc16 = (ks << 2) + kc;
      half8_t ah[4];
#pragma unroll
      for (int m = 0; m < 4; ++m) {
        int r = (m << 4) + c;
        int idx = ((r << 7) + (kc << 5) + (g << 3)) ^ (c << 3);
        ah[m] = *reinterpret_cast<const half8_t*>(&Ah[cur][idx]);
      }
      half8_t bh[4];
#pragma unroll
      for (int n = 0; n < 4; ++n)
        bh[n] = bhb[(((kc16 << 4) + (w << 2) + n) << 6) + l];
#pragma unroll
      for (int n = 0; n < 4; ++n)
#pragma unroll
        for (int m = 0; m < 4; ++m)
          acc[m][n] = __builtin_amdgcn_mfma_f32_16x16x32_f16(ah[m], bh[n], acc[m][n], 0, 0, 0);
    }

    // convert + write next tile into the other buffer
    if (ks < 3) {
      const int nxt = cur ^ 1;
      *reinterpret_cast<half8_t*>(&Ah[nxt][(i0 + 0) ^ sw]) = cvt8(r0, r1);
      *reinterpret_cast<half8_t*>(&Ah[nxt][(i0 + 8) ^ sw]) = cvt8(r2, r3);
      *reinterpret_cast<half8_t*>(&Ah[nxt][(i0 + 16) ^ sw]) = cvt8(r4, r5);
      *reinterpret_cast<half8_t*>(&Ah[nxt][(i0 + 24) ^ sw]) = cvt8(r6, r7);
    }
    __syncthreads();
  }

  // ---- epilogue: bias+relu, fused row-dot + row-norm, normalized store ----
  float bv[4], wv[4];
#pragma unroll
  for (int n = 0; n < 4; ++n) {
    bv[n] = bm[(w << 6) + (n << 4) + c];
    wv[n] = w2[(w << 6) + (n << 4) + c];
  }
#pragma unroll
  for (int m = 0; m < 4; ++m)
#pragma unroll
    for (int n = 0; n < 4; ++n)
#pragma unroll
      for (int q = 0; q < 4; ++q) {
        float v = acc[m][n][q] + bv[n];
        acc[m][n][q] = v > 0.f ? v : 0.f;
      }

  float* red = reinterpret_cast<float*>(&Ah[0][0]);
  float pss[4][4], pdt[4][4];
#pragma unroll
  for (int m = 0; m < 4; ++m)
#pragma unroll
    for (int q = 0; q < 4; ++q) {
      float ss = 0.f, dt = 0.f;
#pragma unroll
      for (int n = 0; n < 4; ++n) {
        float a = acc[m][n][q];
        ss = fmaf(a, a, ss);
        dt = fmaf(a, wv[n], dt);
      }
      for (int d = 8; d; d >>= 1) {
        ss += __shfl_down(ss, d, 16);
        dt += __shfl_down(dt, d, 16);
      }
      pss[m][q] = ss;
      pdt[m][q] = dt;
    }
  __syncthreads();
#pragma unroll
  for (int m = 0; m < 4; ++m)
#pragma unroll
    for (int q = 0; q < 4; ++q)
      if (c == 0) {
        int rr = (m << 4) + (g << 2) + q;
        red[(w << 6) + rr] = pss[m][q];
        red[256 + (w << 6) + rr] = pdt[m][q];
      }
  __syncthreads();
  if (t < 64) {
    float ss = red[t] + red[64 + t] + red[128 + t] + red[192 + t];
    float dt = red[256 + t] + red[320 + t] + red[384 + t] + red[448 + t];
    float nr = sqrtf(ss);
    red[512 + t] = 1.f / fmaxf(nr, 1e-12f);
    int r = row0 + t;
    if (r < M) wnorm[r] = expf(dt) * nr;
  }
  __syncthreads();
#pragma unroll
  for (int m = 0; m < 4; ++m)
#pragma unroll
    for (int q = 0; q < 4; ++q) {
      int rr = (m << 4) + (g << 2) + q;
      float sc = red[512 + rr];
      int r = row0 + rr;
      if (r < M) {
#pragma unroll
        for (int n = 0; n < 4; ++n)
          Yn[(size_t)r * DD + (w << 6) + (n << 4) + c] = acc[m][n][q] * sc;
      }
    }
}

// ---- CSR build ----
__global__ void hist_kernel(const int* __restrict__ src, int* __restrict__ deg, int E) {
  int i = blockIdx.x * blockDim.x + threadIdx.x;
  if (i < E) atomicAdd(&deg[src[i]], 1);
}

// hierarchical exclusive scan: 256 blocks x 256 thr x 2 items
__global__ __launch_bounds__(256) void scan_part(const int* __restrict__ deg,
                                                 int* __restrict__ bsum, int NP) {
  __shared__ int s[256];
  int t = threadIdx.x, b = blockIdx.x;
  int i0 = (b * 256 + t) * 2;
  int v0 = (i0 < NP) ? deg[i0] : 0;
  int v1 = (i0 + 1 < NP) ? deg[i0 + 1] : 0;
  s[t] = v0 + v1;
  __syncthreads();
  for (int off = 128; off; off >>= 1) {
    if (t < off) s[t] += s[t + off];
    __syncthreads();
  }
  if (t == 0) bsum[b] = s[0];
}

__global__ __launch_bounds__(256) void scan_top(int* __restrict__ bsum,
                                                int* __restrict__ rowptr_last) {
  __shared__ int s[256];
  int t = threadIdx.x;
  int v = bsum[t];
  s[t] = v;
  __syncthreads();
  for (int off = 1; off < 256; off <<= 1) {
    int u = (t >= off) ? s[t - off] : 0;
    __syncthreads();
    s[t] += u;
    __syncthreads();
  }
  bsum[t] = s[t] - v;  // exclusive
  if (t == 255) *rowptr_last = s[255];
}

__global__ __launch_bounds__(256) void scan_fin(const int* __restrict__ deg,
                                                const int* __restrict__ bsum,
                                                int* __restrict__ rowptr,
                                                int* __restrict__ cursor, int NP) {
  __shared__ int s[256];
  int t = threadIdx.x, b = blockIdx.x;
  int i0 = (b * 256 + t) * 2;
  int v0 = (i0 < NP) ? deg[i0] : 0;
  int v1 = (i0 + 1 < NP) ? deg[i0 + 1] : 0;
  int local = v0 + v1;
  s[t] = local;
  __syncthreads();
  for (int off = 1; off < 256; off <<= 1) {
    int u = (t >= off) ? s[t - off] : 0;
    __syncthreads();
    s[t] += u;
    __syncthreads();
  }
  int base = bsum[b] + s[t] - local;
  if (i0 < NP) { rowptr[i0] = base; cursor[i0] = base; }
  if (i0 + 1 < NP) { rowptr[i0 + 1] = base + v0; cursor[i0 + 1] = base + v0; }
}

__global__ void fill_kernel(const int* __restrict__ src, const int* __restrict__ dst,
                            int* __restrict__ cursor, int* __restrict__ ebuf, int E) {
  int i = blockIdx.x * blockDim.x + threadIdx.x;
  if (i < E) {
    int pos = atomicAdd(&cursor[src[i]], 1);
    ebuf[pos] = dst[i];
  }
}

// ---- per-segment: out = l2norm(sum wnorm[d] * hon[d])
// (softmax denom is a positive segment constant -> vanishes under l2norm) ----
__global__ void agg_kernel(const int* __restrict__ rowptr, const int* __restrict__ ebuf,
                           const float* __restrict__ wnorm, const float* __restrict__ hon,
                           float* __restrict__ agg, int NP) {
  int p = (int)(((long)blockIdx.x * blockDim.x + threadIdx.x) >> 6);
  int lane = threadIdx.x & 63;
  if (p >= NP) return;
  int beg = rowptr[p], end = rowptr[p + 1];
  float4 acc = {0.f, 0.f, 0.f, 0.f};
  if (beg < end) {
    // 2-deep pipelined weighted row gather
    int d0 = ebuf[beg];
    float w0 = wnorm[d0];
    float4 v0 = *reinterpret_cast<const float4*>(&hon[(size_t)d0 * DD + lane * 4]);
    float w1 = 0.f;
    float4 v1 = {0.f, 0.f, 0.f, 0.f};
    if (beg + 1 < end) {
      int d1 = ebuf[beg + 1];
      w1 = wnorm[d1];
      v1 = *reinterpret_cast<const float4*>(&hon[(size_t)d1 * DD + lane * 4]);
    }
    for (int j = beg; j < end; ++j) {
      float wn_ = 0.f;
      float4 vn = {0.f, 0.f, 0.f, 0.f};
      if (j + 2 < end) {
        int dn = ebuf[j + 2];
        wn_ = wnorm[dn];
        vn = *reinterpret_cast<const float4*>(&hon[(size_t)dn * DD + lane * 4]);
      }
      acc.x = fmaf(w0, v0.x, acc.x);
      acc.y = fmaf(w0, v0.y, acc.y);
      acc.z = fmaf(w0, v0.z, acc.z);
      acc.w = fmaf(w0, v0.w, acc.w);
      w0 = w1; v0 = v1; w1 = wn_; v1 = vn;
    }
  }
  float ss = acc.x * acc.x + acc.y * acc.y + acc.z * acc.z + acc.w * acc.w;
#pragma unroll
  for (int d = 32; d > 0; d >>= 1) ss += __shfl_xor(ss, d, 64);
  float inv = 1.0f / fmaxf(sqrtf(ss), 1e-12f);
  float4 o = {acc.x * inv, acc.y * inv, acc.z * inv, acc.w * inv};
  *reinterpret_cast<float4*>(&agg[(size_t)p * DD + lane * 4]) = o;
}

extern "C" void kernel_launch(void* const* d_in, const int* in_sizes, int n_in,
                              void* d_out, int out_size, void* d_ws, size_t ws_size,
                              hipStream_t stream) {
  const float* feat_other = (const float*)d_in[1];
  const int* src = (const int*)d_in[2];
  const int* dst = (const int*)d_in[3];
  const float* Wm_o = (const float*)d_in[6];
  const float* bm_o = (const float*)d_in[7];
  const float* W = (const float*)d_in[8];
  const float* a_w = (const float*)d_in[10];

  const int NP = in_sizes[0] / IN_DIM;
  const int NO = in_sizes[1] / IN_DIM;
  const int E = in_sizes[2];

  float* out = (float*)d_out;
  float* agg_out = out;                      // [NP, DD] (normalized agg)
  float* ho_out = out + (size_t)NP * DD;     // [NO, DD] (normalized ho)

  // workspace layout (floats)
  float* ws = (float*)d_ws;
  float* wnorm = ws;                          // NO
  float* w2 = wnorm + NO;                     // 256
  int* deg = (int*)(w2 + 256);                // NP (memset 0)
  int* rowptr = deg + NP;                     // NP+1
  int* cursor = rowptr + NP + 1;              // NP
  int* bsum = cursor + NP;                    // 256
  int* ebuf = bsum + 256;                     // E
  size_t foff = (size_t)NO + 256 + NP + (NP + 1) + NP + 256 + E;
  foff = (foff + 3) & ~(size_t)3;             // 16B align
  _Float16* Bh = (_Float16*)(ws + foff);      // 131072 halves

  hipMemsetAsync(deg, 0, (size_t)NP * sizeof(int), stream);

  prep_w2<<<1, 256, 0, stream>>>(W, a_w, w2);
  bconv_kernel<<<(IN_DIM * DD) / 256, 256, 0, stream>>>(Wm_o, Bh);

  map_gemm_mfma<<<(NO + 63) / 64, 256, 0, stream>>>(
      feat_other, Bh, bm_o, w2, ho_out, wnorm, NO);

  hist_kernel<<<(E + 255) / 256, 256, 0, stream>>>(src, deg, E);
  scan_part<<<256, 256, 0, stream>>>(deg, bsum, NP);
  scan_top<<<1, 256, 0, stream>>>(bsum, rowptr + NP);
  scan_fin<<<256, 256, 0, stream>>>(deg, bsum, rowptr, cursor, NP);
  fill_kernel<<<(E + 255) / 256, 256, 0, stream>>>(src, dst, cursor, ebuf, E);

  agg_kernel<<<(NP * 64 + 255) / 256, 256, 0, stream>>>(
      rowptr, ebuf, wnorm, ho_out, agg_out, NP);
}